// Round 9
// baseline (387.376 us; speedup 1.0000x reference)
//
#include <hip/hip_runtime.h>

#define N_NODES 100000
#define N_EDGES 1600000
#define IN_DIM  128
#define C1      64     // hidden = 4 heads * 16
#define H1      4
#define F1      16
#define C2      16
#define NEG     0.2f
#define EPS_    1e-9f

#define NB      782            // buckets of 128 receivers
#define HB      128            // hist / place blocks
#define EPB     (N_EDGES/HB)   // 12500 edges per hist/place block
#define MSZ     (NB*HB)        // 100096 count-matrix entries
#define G1B     391            // gemm1 blocks inside k_h1g
#define BK_CAP  2560           // max edges per bucket (mean 2048, 11 sigma)

typedef _Float16 half8 __attribute__((ext_vector_type(8)));
typedef _Float16 half4 __attribute__((ext_vector_type(4)));
typedef float float4v __attribute__((ext_vector_type(4)));

__device__ __forceinline__ float lrelu(float x) { return x > 0.f ? x : NEG * x; }

// ================= k_h1g: layer-1 GEMM (MFMA, LDS-built WT1) + bucket hist =================
// Blocks 0..G1B-1: gemm (16 waves x 16 nodes). Blocks G1B..G1B+127: LDS histogram
// of recv>>7 into count matrix M[bin][hb]. No global atomics anywhere.

__global__ __launch_bounds__(1024) void k_h1g(
    const float* __restrict__ x, const float* __restrict__ W1,
    const float* __restrict__ a1s, const float* __restrict__ a1d,
    _Float16* __restrict__ h1, _Float16* __restrict__ ssh, float* __restrict__ sd,
    const int* __restrict__ recv, int* __restrict__ M) {
  __shared__ _Float16 WT1L[80 * 136];   // rows 0-63 W1cat^T, 64-71 fused a-vecs; +8 pad
  __shared__ int hc[NB];
  int b = blockIdx.x, t = threadIdx.x;

  if (b >= G1B) {                       // ---- histogram part ----
    int hb = b - G1B;
    for (int i = t; i < NB; i += 1024) hc[i] = 0;
    __syncthreads();
    int e1 = (hb + 1) * EPB;
    for (int e = hb * EPB + t; e < e1; e += 1024)
      atomicAdd(&hc[recv[e] >> 7], 1);  // LDS atomic
    __syncthreads();
    for (int i = t; i < NB; i += 1024) M[i * HB + hb] = hc[i];
    return;
  }

  // ---- build WT1 in LDS (20.5 KB padded) ----
  for (int i = t; i < 80 * 128; i += 1024) {
    int c = i >> 7, k = i & 127;
    float v;
    if (c < 64) v = W1[(c >> 4) * 2048 + k * 16 + (c & 15)];
    else {
      int h = (c - 64) & 3;
      const float* a = (c < 68) ? a1s : a1d;
      float s = 0.f;
      for (int f = 0; f < 16; ++f) s += W1[h * 2048 + k * 16 + f] * a[h * 16 + f];
      v = s;
    }
    WT1L[c * 136 + k] = (_Float16)v;
  }
  __syncthreads();

  int wave = b * 16 + (t >> 6);
  int n0 = wave * 16;
  if (n0 >= N_NODES) return;
  int lane = t & 63;
  int mrow = lane & 15, quad = lane >> 4;
  const float* xrow = x + (size_t)(n0 + mrow) * IN_DIM + quad * 8;
  float4v acc[5];
#pragma unroll
  for (int i = 0; i < 5; ++i) acc[i] = (float4v)(0.f);
#pragma unroll
  for (int kt = 0; kt < 4; ++kt) {
    float4 a0 = *(const float4*)(xrow + kt * 32);
    float4 a1 = *(const float4*)(xrow + kt * 32 + 4);
    half8 af;
    af[0] = (_Float16)a0.x; af[1] = (_Float16)a0.y; af[2] = (_Float16)a0.z; af[3] = (_Float16)a0.w;
    af[4] = (_Float16)a1.x; af[5] = (_Float16)a1.y; af[6] = (_Float16)a1.z; af[7] = (_Float16)a1.w;
#pragma unroll
    for (int i = 0; i < 5; ++i) {
      half8 bf = *(const half8*)(WT1L + (i * 16 + mrow) * 136 + kt * 32 + quad * 8);
      acc[i] = __builtin_amdgcn_mfma_f32_16x16x32_f16(af, bf, acc[i], 0, 0, 0);
    }
  }
#pragma unroll
  for (int i = 0; i < 4; ++i)
#pragma unroll
    for (int r = 0; r < 4; ++r)
      h1[(size_t)(n0 + quad * 4 + r) * C1 + i * 16 + mrow] = (_Float16)acc[i][r];
  if (mrow < 8) {
#pragma unroll
    for (int r = 0; r < 4; ++r) {
      int n = n0 + quad * 4 + r;
      float v = acc[4][r];
      if (mrow < 4) ssh[n * 4 + mrow] = (_Float16)v;
      else          sd[n * 4 + (mrow - 4)] = v;
    }
  }
}

// ================= k_p1s: per-block redundant scan of M + edge placement =================
// Every block scans the full 100096-entry matrix (L2-resident, ~2us) and extracts
// its own 782 cursors — removes both scan dispatches. Block 0 emits bucket starts.

__global__ __launch_bounds__(1024) void k_p1s(
    const int* __restrict__ recv, const int* __restrict__ send,
    const int* __restrict__ M, unsigned* __restrict__ tmp, int* __restrict__ bstart) {
  __shared__ int cur[NB];
  __shared__ int ws[16];
  int blk = blockIdx.x, t = threadIdx.x;
  int lo = t * 98, hi = min(lo + 98, MSZ);
  int sum = 0;
  for (int p = lo; p < hi; ++p) sum += M[p];
  // block-wide exclusive scan of 1024 partials
  int l = t & 63, w = t >> 6, s = sum;
#pragma unroll
  for (int off = 1; off < 64; off <<= 1) { int u = __shfl_up(s, off); if (l >= off) s += u; }
  if (l == 63) ws[w] = s;
  __syncthreads();
  if (t < 16) {
    int p = ws[t];
#pragma unroll
    for (int off = 1; off < 16; off <<= 1) { int u = __shfl_up(p, off); if (t >= off) p += u; }
    ws[t] = p;
  }
  __syncthreads();
  int run = ((w > 0) ? ws[w - 1] : 0) + s - sum;
  for (int p = lo; p < hi; ++p) {
    int v = M[p];
    if ((p & 127) == blk) {
      cur[p >> 7] = run;
      if (blk == 0) bstart[p >> 7] = run;
    }
    run += v;
  }
  if (blk == 0 && t == 0) bstart[NB] = N_EDGES;
  __syncthreads();
  int e1 = (blk + 1) * EPB;
  for (int e = blk * EPB + t; e < e1; e += 1024) {
    int r = recv[e], sn = send[e];
    int pos = atomicAdd(&cur[r >> 7], 1);       // LDS returning atomic
    tmp[pos] = ((unsigned)(r & 127) << 17) | (unsigned)sn;
  }
}

// ================= k_aggA: per-bucket sort (LDS) + layer-1 agg + fused gemm2 =================
// One block (256 thr, 4 waves) per 128-receiver bucket: counting-sort ~2048 edges
// into LDS csr (global rs/csr written only for agg2), aggregate 128 nodes from LDS
// with 16 gathers in flight, then per-node z (fp32, never hits HBM) -> h2/ss2/sd2.

__global__ __launch_bounds__(256) void k_aggA(
    const int* __restrict__ bstart, const unsigned* __restrict__ tmp,
    const _Float16* __restrict__ ssh, const float* __restrict__ sdst,
    const _Float16* __restrict__ h1,
    const float* __restrict__ W2, const float* __restrict__ a2s, const float* __restrict__ a2d,
    int* __restrict__ rs, int* __restrict__ csr,
    _Float16* __restrict__ h2, float* __restrict__ ss2, float* __restrict__ sd2) {
  __shared__ int lcsr[BK_CAP];
  __shared__ int lrs[129];
  __shared__ int cnt[128];
  __shared__ float zbuf[4][64];
  __shared__ _Float16 WT2T[64 * 32];   // [k][c]: c<16 W2^T, 16 a2s-fused, 17 a2d-fused
  int b = blockIdx.x, t = threadIdx.x;
  int e0 = bstart[b], e1 = bstart[b + 1];
  int wid0 = b * 128;

  for (int i = t; i < 64 * 32; i += 256) {
    int k = i >> 5, c = i & 31;
    float v = 0.f;
    if (c < 16) v = W2[k * 16 + c];
    else if (c == 16) { for (int f = 0; f < 16; ++f) v += W2[k * 16 + f] * a2s[f]; }
    else if (c == 17) { for (int f = 0; f < 16; ++f) v += W2[k * 16 + f] * a2d[f]; }
    WT2T[i] = (_Float16)v;
  }
  if (t < 128) cnt[t] = 0;
  __syncthreads();
  for (int e = e0 + t; e < e1; e += 256) atomicAdd(&cnt[tmp[e] >> 17], 1);
  __syncthreads();
  if (t == 0) {                       // 128-entry serial scan (cheap, once per block)
    int a = 0;
    for (int i = 0; i < 128; ++i) { int v = cnt[i]; lrs[i] = a; a += v; }
    lrs[128] = a;
  }
  __syncthreads();
  if (t < 128 && wid0 + t <= N_NODES) rs[wid0 + t] = e0 + lrs[t];
  if (t < 128) cnt[t] = lrs[t];       // becomes cursor
  __syncthreads();
  for (int e = e0 + t; e < e1; e += 256) {
    unsigned u = tmp[e];
    int pos = atomicAdd(&cnt[u >> 17], 1);
    int sn = (int)(u & 0x1FFFFu);
    lcsr[pos] = sn;
    csr[e0 + pos] = sn;               // for agg2
  }
  __syncthreads();

  // ---- aggregation: wave w handles local nodes w*32 .. w*32+31 ----
  int wave = t >> 6, lane = t & 63;
  int g = lane >> 4, f = lane & 15, h = f >> 2;
  for (int ni = 0; ni < 32; ++ni) {
    int ln = wave * 32 + ni;
    int wid = wid0 + ln;
    if (wid >= N_NODES) break;        // wave-uniform
    int start = lrs[ln], deg = lrs[ln + 1] - start;
    float sdh = sdst[wid * 4 + h];
    float a0 = 0.f, a1 = 0.f, a2 = 0.f, a3 = 0.f, dsum = 0.f;
    for (int j0 = 0; j0 < deg; j0 += 16) {
      int jA = j0 + g, jB = j0 + 4 + g, jC = j0 + 8 + g, jD = j0 + 12 + g;
      int sA = lcsr[start + (jA < deg ? jA : 0)];
      int sB = lcsr[start + (jB < deg ? jB : 0)];
      int sC = lcsr[start + (jC < deg ? jC : 0)];
      int sD = lcsr[start + (jD < deg ? jD : 0)];
      float eA = (float)ssh[sA * 4 + h];
      float eB = (float)ssh[sB * 4 + h];
      float eC = (float)ssh[sC * 4 + h];
      float eD = (float)ssh[sD * 4 + h];
      half4 hA = *(const half4*)(h1 + (size_t)sA * C1 + f * 4);
      half4 hB = *(const half4*)(h1 + (size_t)sB * C1 + f * 4);
      half4 hC = *(const half4*)(h1 + (size_t)sC * C1 + f * 4);
      half4 hD = *(const half4*)(h1 + (size_t)sD * C1 + f * 4);
      float alA = (jA < deg) ? __expf(lrelu(eA + sdh)) : 0.f;
      float alB = (jB < deg) ? __expf(lrelu(eB + sdh)) : 0.f;
      float alC = (jC < deg) ? __expf(lrelu(eC + sdh)) : 0.f;
      float alD = (jD < deg) ? __expf(lrelu(eD + sdh)) : 0.f;
      dsum += (alA + alB) + (alC + alD);
      a0 = fmaf(alA, (float)hA[0], fmaf(alB, (float)hB[0], fmaf(alC, (float)hC[0], fmaf(alD, (float)hD[0], a0))));
      a1 = fmaf(alA, (float)hA[1], fmaf(alB, (float)hB[1], fmaf(alC, (float)hC[1], fmaf(alD, (float)hD[1], a1))));
      a2 = fmaf(alA, (float)hA[2], fmaf(alB, (float)hB[2], fmaf(alC, (float)hC[2], fmaf(alD, (float)hD[2], a2))));
      a3 = fmaf(alA, (float)hA[3], fmaf(alB, (float)hB[3], fmaf(alC, (float)hC[3], fmaf(alD, (float)hD[3], a3))));
    }
#pragma unroll
    for (int off = 16; off <= 32; off <<= 1) {
      a0 += __shfl_xor(a0, off); a1 += __shfl_xor(a1, off);
      a2 += __shfl_xor(a2, off); a3 += __shfl_xor(a3, off);
      dsum += __shfl_xor(dsum, off);
    }
    if (g == 0) {                      // fp32 z row (with ELU) -> per-wave LDS
      float inv = 1.f / (dsum + EPS_);
      float v0 = a0 * inv, v1 = a1 * inv, v2 = a2 * inv, v3 = a3 * inv;
      zbuf[wave][f * 4 + 0] = v0 > 0.f ? v0 : __expf(v0) - 1.f;
      zbuf[wave][f * 4 + 1] = v1 > 0.f ? v1 : __expf(v1) - 1.f;
      zbuf[wave][f * 4 + 2] = v2 > 0.f ? v2 : __expf(v2) - 1.f;
      zbuf[wave][f * 4 + 3] = v3 > 0.f ? v3 : __expf(v3) - 1.f;
    }
    // wave-synchronous LDS use (no barrier needed); compiler inserts lgkmcnt waits
    if (lane < 18) {
      float a = 0.f;
#pragma unroll
      for (int k = 0; k < 64; ++k)
        a = fmaf(zbuf[wave][k], (float)WT2T[k * 32 + lane], a);
      if (lane < 16)       h2[(size_t)wid * C2 + lane] = (_Float16)a;
      else if (lane == 16) ss2[wid] = a;
      else                 sd2[wid] = a;
    }
  }
}

// ================= k_agg2: layer-2 aggregation, 32 edges in flight =================

__global__ __launch_bounds__(256) void k_agg2(
    const int* __restrict__ rs, const int* __restrict__ csr,
    const float* __restrict__ ss2, const float* __restrict__ sd2,
    const _Float16* __restrict__ h2, float* __restrict__ out) {
  int wid = (blockIdx.x * 256 + threadIdx.x) >> 6;
  if (wid >= N_NODES) return;
  int lane = threadIdx.x & 63;
  int g = lane >> 2, q = lane & 3;
  int start = rs[wid], deg = rs[wid + 1] - start;
  float sd = sd2[wid];
  float a0 = 0.f, a1 = 0.f, a2 = 0.f, a3 = 0.f, dsum = 0.f;
  for (int j0 = 0; j0 < deg; j0 += 32) {
    int jA = j0 + g, jB = j0 + 16 + g;
    int sA = csr[start + (jA < deg ? jA : 0)];
    int sB = csr[start + (jB < deg ? jB : 0)];
    float eA = ss2[sA], eB = ss2[sB];
    half4 hA = *(const half4*)(h2 + (size_t)sA * C2 + q * 4);
    half4 hB = *(const half4*)(h2 + (size_t)sB * C2 + q * 4);
    float alA = (jA < deg) ? __expf(lrelu(eA + sd)) : 0.f;
    float alB = (jB < deg) ? __expf(lrelu(eB + sd)) : 0.f;
    dsum += alA + alB;
    a0 = fmaf(alA, (float)hA[0], fmaf(alB, (float)hB[0], a0));
    a1 = fmaf(alA, (float)hA[1], fmaf(alB, (float)hB[1], a1));
    a2 = fmaf(alA, (float)hA[2], fmaf(alB, (float)hB[2], a2));
    a3 = fmaf(alA, (float)hA[3], fmaf(alB, (float)hB[3], a3));
  }
#pragma unroll
  for (int off = 4; off <= 32; off <<= 1) {
    a0 += __shfl_xor(a0, off); a1 += __shfl_xor(a1, off);
    a2 += __shfl_xor(a2, off); a3 += __shfl_xor(a3, off);
    dsum += __shfl_xor(dsum, off);
  }
  if (g == 0) {
    float inv = 1.f / (dsum + EPS_);
    float4 o = make_float4(a0 * inv, a1 * inv, a2 * inv, a3 * inv);
    *(float4*)(out + (size_t)wid * C2 + q * 4) = o;
  }
}

// ================= launch: 4 dispatches =================

extern "C" void kernel_launch(void* const* d_in, const int* in_sizes, int n_in,
                              void* d_out, int out_size, void* d_ws, size_t ws_size,
                              hipStream_t stream) {
  const float* x    = (const float*)d_in[0];
  const int* senders   = (const int*)d_in[1];
  const int* receivers = (const int*)d_in[2];
  const float* W1  = (const float*)d_in[3];
  const float* a1s = (const float*)d_in[4];
  const float* a1d = (const float*)d_in[5];
  const float* W2  = (const float*)d_in[6];
  const float* a2s = (const float*)d_in[7];
  const float* a2d = (const float*)d_in[8];
  float* out = (float*)d_out;

  char* w = (char*)d_ws;
  _Float16* h1   = (_Float16*)(w + 0);          // 12,800,000 B [N][64]
  _Float16* ssh1 = (_Float16*)(w + 12800000);   //    800,000 B [N][4]
  float* sd1 = (float*)(w + 13600000);          //  1,600,000 B [N][4]
  _Float16* h2   = (_Float16*)(w + 15200000);   //  3,200,000 B [N][16]
  float* ss2 = (float*)(w + 18400000);          //    400,000 B [N]
  float* sd2 = (float*)(w + 18800000);          //    400,000 B [N]
  int*   rs  = (int*)  (w + 19200000);          //    400,128 B [N+1]
  int*   csr = (int*)  (w + 19600128);          //  6,400,000 B
  unsigned* tmp = (unsigned*)(w + 26000128);    //  6,400,000 B
  int*   M   = (int*)  (w + 32400128);          //    400,384 B [782][128]
  int*   bst = (int*)  (w + 32800512);          //      3,132 B [783]
  // total ~32.8 MB

  k_h1g <<<G1B + HB, 1024, 0, stream>>>(x, W1, a1s, a1d, h1, ssh1, sd1, receivers, M);
  k_p1s <<<HB, 1024, 0, stream>>>(receivers, senders, M, tmp, bst);
  k_aggA<<<NB, 256, 0, stream>>>(bst, tmp, ssh1, sd1, h1, W2, a2s, a2d,
                                 rs, csr, h2, ss2, sd2);
  k_agg2<<<25000, 256, 0, stream>>>(rs, csr, ss2, sd2, h2, out);
}

// Round 10
// 318.009 us; speedup vs baseline: 1.2181x; 1.2181x over previous
//
#include <hip/hip_runtime.h>

#define N_NODES 100000
#define N_EDGES 1600000
#define IN_DIM  128
#define C1      64     // hidden = 4 heads * 16
#define H1      4
#define F1      16
#define C2      16
#define NEG     0.2f
#define EPS_    1e-9f

#define NHB     256            // hist blocks (and matrix columns)
#define EPB     (N_EDGES/NHB)  // 6250 edges per hist/p1 block
#define G1B     391            // gemm1 blocks in fused kernel
#define NBUCK   196            // ceil(100000/512) non-empty buckets

typedef _Float16 half8 __attribute__((ext_vector_type(8)));
typedef _Float16 half4 __attribute__((ext_vector_type(4)));
typedef float float4v __attribute__((ext_vector_type(4)));

__device__ __forceinline__ float lrelu(float x) { return x > 0.f ? x : NEG * x; }

// ================= k_h1g: layer-1 GEMM (MFMA, LDS-built WT1) + bucket hist =================
// Blocks 0..G1B-1: gemm (16 waves x 16 nodes), WT1 built in LDS (kills k_pre).
// Blocks G1B..G1B+255: LDS histogram of recv>>9 into M[bin][hb]. No global atomics.

__global__ __launch_bounds__(1024) void k_h1g(
    const float* __restrict__ x, const float* __restrict__ W1,
    const float* __restrict__ a1s, const float* __restrict__ a1d,
    _Float16* __restrict__ h1, _Float16* __restrict__ ssh, float* __restrict__ sd,
    const int* __restrict__ recv, int* __restrict__ M) {
  __shared__ _Float16 WT1L[80 * 136];   // rows 0-63 W1cat^T, 64-71 fused a-vecs; +8 pad
  __shared__ int hc[NHB];
  int b = blockIdx.x, t = threadIdx.x;

  if (b >= G1B) {                       // ---- histogram part ----
    int hb = b - G1B;
    if (t < NHB) hc[t] = 0;
    __syncthreads();
    int e1 = (hb + 1) * EPB;
    for (int e = hb * EPB + t; e < e1; e += 1024)
      atomicAdd(&hc[recv[e] >> 9], 1);  // LDS atomic
    __syncthreads();
    if (t < NHB) M[t * NHB + hb] = hc[t];
    return;
  }

  // ---- build WT1 in LDS ----
  for (int i = t; i < 80 * 128; i += 1024) {
    int c = i >> 7, k = i & 127;
    float v;
    if (c < 64) v = W1[(c >> 4) * 2048 + k * 16 + (c & 15)];
    else {
      int h = (c - 64) & 3;
      const float* a = (c < 68) ? a1s : a1d;
      float s = 0.f;
      for (int f = 0; f < 16; ++f) s += W1[h * 2048 + k * 16 + f] * a[h * 16 + f];
      v = s;
    }
    WT1L[c * 136 + k] = (_Float16)v;
  }
  __syncthreads();

  int wave = b * 16 + (t >> 6);
  int n0 = wave * 16;
  if (n0 >= N_NODES) return;
  int lane = t & 63;
  int mrow = lane & 15, quad = lane >> 4;
  const float* xrow = x + (size_t)(n0 + mrow) * IN_DIM + quad * 8;
  float4v acc[5];
#pragma unroll
  for (int i = 0; i < 5; ++i) acc[i] = (float4v)(0.f);
#pragma unroll
  for (int kt = 0; kt < 4; ++kt) {
    float4 a0 = *(const float4*)(xrow + kt * 32);
    float4 a1 = *(const float4*)(xrow + kt * 32 + 4);
    half8 af;
    af[0] = (_Float16)a0.x; af[1] = (_Float16)a0.y; af[2] = (_Float16)a0.z; af[3] = (_Float16)a0.w;
    af[4] = (_Float16)a1.x; af[5] = (_Float16)a1.y; af[6] = (_Float16)a1.z; af[7] = (_Float16)a1.w;
#pragma unroll
    for (int i = 0; i < 5; ++i) {
      half8 bf = *(const half8*)(WT1L + (i * 16 + mrow) * 136 + kt * 32 + quad * 8);
      acc[i] = __builtin_amdgcn_mfma_f32_16x16x32_f16(af, bf, acc[i], 0, 0, 0);
    }
  }
#pragma unroll
  for (int i = 0; i < 4; ++i)
#pragma unroll
    for (int r = 0; r < 4; ++r)
      h1[(size_t)(n0 + quad * 4 + r) * C1 + i * 16 + mrow] = (_Float16)acc[i][r];
  if (mrow < 8) {
#pragma unroll
    for (int r = 0; r < 4; ++r) {
      int n = n0 + quad * 4 + r;
      float v = acc[4][r];
      if (mrow < 4) ssh[n * 4 + mrow] = (_Float16)v;
      else          sd[n * 4 + (mrow - 4)] = v;
    }
  }
}

// ================= coalesced scans of the 65536-entry count matrix =================

__global__ __launch_bounds__(1024) void k_scanA(int* __restrict__ M, int* __restrict__ bs) {
  __shared__ int ws[16];
  int t = threadIdx.x, g = blockIdx.x * 1024 + t;
  int v = M[g];
  int s = v, l = t & 63;
#pragma unroll
  for (int off = 1; off < 64; off <<= 1) { int u = __shfl_up(s, off); if (l >= off) s += u; }
  if (l == 63) ws[t >> 6] = s;
  __syncthreads();
  if (t < 16) {
    int p = ws[t];
#pragma unroll
    for (int off = 1; off < 16; off <<= 1) { int u = __shfl_up(p, off); if (t >= off) p += u; }
    ws[t] = p;
  }
  __syncthreads();
  int base = (t >= 64) ? ws[(t >> 6) - 1] : 0;
  M[g] = base + s - v;
  if (t == 1023) bs[blockIdx.x] = base + s;
}

__global__ __launch_bounds__(1024) void k_scanB(int* __restrict__ M, const int* __restrict__ bs) {
  __shared__ int sm[64];
  int t = threadIdx.x;
  if (t < 64) sm[t] = bs[t];
  __syncthreads();
  if (t == 0) { int a = 0; for (int i = 0; i < 64; ++i) { int v = sm[i]; sm[i] = a; a += v; } }
  __syncthreads();
  M[blockIdx.x * 1024 + t] += sm[blockIdx.x];
}

// ================= p1: place edges into bucket-grouped tmp via LDS cursors =================

__global__ __launch_bounds__(1024) void k_p1(
    const int* __restrict__ recv, const int* __restrict__ send,
    const int* __restrict__ Ms, unsigned* __restrict__ tmp) {
  __shared__ int cur[NHB];
  int blk = blockIdx.x, t = threadIdx.x;
  if (t < NHB) cur[t] = Ms[t * NHB + blk];
  __syncthreads();
  int e1 = (blk + 1) * EPB;
  for (int e = blk * EPB + t; e < e1; e += 1024) {
    int r = recv[e], s = send[e];
    int pos = atomicAdd(&cur[r >> 9], 1);
    tmp[pos] = ((unsigned)(r & 511) << 17) | (unsigned)s;
  }
}

// ================= p2: per-bucket counting sort -> rs + csr =================

__global__ __launch_bounds__(1024) void k_p2(
    const int* __restrict__ Ms, const unsigned* __restrict__ tmp,
    int* __restrict__ rs, int* __restrict__ csr) {
  __shared__ int cnt[512];
  __shared__ int wt[8];
  int b = blockIdx.x, t = threadIdx.x;
  int e0 = Ms[b * NHB];
  int e1 = Ms[(b + 1) * NHB];
  if (t < 512) cnt[t] = 0;
  __syncthreads();
  for (int e = e0 + t; e < e1; e += 1024)
    atomicAdd(&cnt[tmp[e] >> 17], 1);
  __syncthreads();
  int v = (t < 512) ? cnt[t] : 0;
  int l = t & 63, s = v;
#pragma unroll
  for (int off = 1; off < 64; off <<= 1) { int u = __shfl_up(s, off); if (l >= off) s += u; }
  if (t < 512 && l == 63) wt[t >> 6] = s;
  __syncthreads();
  if (t < 8) {
    int p = wt[t];
#pragma unroll
    for (int off = 1; off < 8; off <<= 1) { int u = __shfl_up(p, off); if (t >= off) p += u; }
    wt[t] = p;
  }
  __syncthreads();
  int base = (t >= 64 && t < 512) ? wt[(t >> 6) - 1] : 0;
  int excl = e0 + base + s - v;
  int idx = b * 512 + t;
  if (t < 512 && idx <= N_NODES) rs[idx] = excl;
  __syncthreads();
  if (t < 512) cnt[t] = excl;
  __syncthreads();
  for (int e = e0 + t; e < e1; e += 1024) {
    unsigned u = tmp[e];
    int pos = atomicAdd(&cnt[u >> 17], 1);
    csr[pos] = (int)(u & 0x1FFFFu);
  }
}

// ================= k_agg1: layer-1 agg (16 edges in flight) + fused gemm2 epilogue =================
// z never hits memory: per-wave fp32 zbuf in LDS; lanes 0-17 compute h2/ss2/sd2
// via an LDS WT2 table ([k][c], c<16 = W2^T, 16 = W2@a2s, 17 = W2@a2d).

__global__ __launch_bounds__(256) void k_agg1(
    const int* __restrict__ rs, const int* __restrict__ csr,
    const _Float16* __restrict__ ssh, const float* __restrict__ sdst,
    const _Float16* __restrict__ h1,
    const float* __restrict__ W2, const float* __restrict__ a2s, const float* __restrict__ a2d,
    _Float16* __restrict__ h2, float* __restrict__ ss2, float* __restrict__ sd2) {
  __shared__ _Float16 WT2T[64 * 18];
  __shared__ float zbuf[4][64];
  int t = threadIdx.x;
  for (int i = t; i < 64 * 18; i += 256) {
    int k = i / 18, c = i - k * 18;
    float v = 0.f;
    if (c < 16) v = W2[k * 16 + c];
    else if (c == 16) { for (int f = 0; f < 16; ++f) v += W2[k * 16 + f] * a2s[f]; }
    else              { for (int f = 0; f < 16; ++f) v += W2[k * 16 + f] * a2d[f]; }
    WT2T[i] = (_Float16)v;
  }
  __syncthreads();

  int wid = (blockIdx.x * 256 + t) >> 6;
  if (wid >= N_NODES) return;          // never triggers at 25000 blocks (exact cover)
  int wave = t >> 6, lane = t & 63;
  int g = lane >> 4, f = lane & 15, h = f >> 2;
  int start = rs[wid], deg = rs[wid + 1] - start;
  float sdh = sdst[wid * 4 + h];
  float a0 = 0.f, a1 = 0.f, a2 = 0.f, a3 = 0.f, dsum = 0.f;
  for (int j0 = 0; j0 < deg; j0 += 16) {
    int jA = j0 + g, jB = j0 + 4 + g, jC = j0 + 8 + g, jD = j0 + 12 + g;
    int sA = csr[start + (jA < deg ? jA : 0)];
    int sB = csr[start + (jB < deg ? jB : 0)];
    int sC = csr[start + (jC < deg ? jC : 0)];
    int sD = csr[start + (jD < deg ? jD : 0)];
    float eA = (float)ssh[sA * 4 + h];
    float eB = (float)ssh[sB * 4 + h];
    float eC = (float)ssh[sC * 4 + h];
    float eD = (float)ssh[sD * 4 + h];
    half4 hA = *(const half4*)(h1 + (size_t)sA * C1 + f * 4);
    half4 hB = *(const half4*)(h1 + (size_t)sB * C1 + f * 4);
    half4 hC = *(const half4*)(h1 + (size_t)sC * C1 + f * 4);
    half4 hD = *(const half4*)(h1 + (size_t)sD * C1 + f * 4);
    float alA = (jA < deg) ? __expf(lrelu(eA + sdh)) : 0.f;
    float alB = (jB < deg) ? __expf(lrelu(eB + sdh)) : 0.f;
    float alC = (jC < deg) ? __expf(lrelu(eC + sdh)) : 0.f;
    float alD = (jD < deg) ? __expf(lrelu(eD + sdh)) : 0.f;
    dsum += (alA + alB) + (alC + alD);
    a0 = fmaf(alA, (float)hA[0], fmaf(alB, (float)hB[0], fmaf(alC, (float)hC[0], fmaf(alD, (float)hD[0], a0))));
    a1 = fmaf(alA, (float)hA[1], fmaf(alB, (float)hB[1], fmaf(alC, (float)hC[1], fmaf(alD, (float)hD[1], a1))));
    a2 = fmaf(alA, (float)hA[2], fmaf(alB, (float)hB[2], fmaf(alC, (float)hC[2], fmaf(alD, (float)hD[2], a2))));
    a3 = fmaf(alA, (float)hA[3], fmaf(alB, (float)hB[3], fmaf(alC, (float)hC[3], fmaf(alD, (float)hD[3], a3))));
  }
#pragma unroll
  for (int off = 16; off <= 32; off <<= 1) {
    a0 += __shfl_xor(a0, off); a1 += __shfl_xor(a1, off);
    a2 += __shfl_xor(a2, off); a3 += __shfl_xor(a3, off);
    dsum += __shfl_xor(dsum, off);
  }
  if (g == 0) {                        // fp32 z row (with ELU) -> per-wave LDS
    float inv = 1.f / (dsum + EPS_);
    float v0 = a0 * inv, v1 = a1 * inv, v2 = a2 * inv, v3 = a3 * inv;
    zbuf[wave][f * 4 + 0] = v0 > 0.f ? v0 : __expf(v0) - 1.f;
    zbuf[wave][f * 4 + 1] = v1 > 0.f ? v1 : __expf(v1) - 1.f;
    zbuf[wave][f * 4 + 2] = v2 > 0.f ? v2 : __expf(v2) - 1.f;
    zbuf[wave][f * 4 + 3] = v3 > 0.f ? v3 : __expf(v3) - 1.f;
  }
  // wave-synchronous LDS (same wave wrote zbuf; compiler inserts lgkmcnt waits)
  if (lane < 18) {
    float a = 0.f;
#pragma unroll
    for (int k = 0; k < 64; ++k)
      a = fmaf(zbuf[wave][k], (float)WT2T[k * 18 + lane], a);
    if (lane < 16)       h2[(size_t)wid * C2 + lane] = (_Float16)a;
    else if (lane == 16) ss2[wid] = a;
    else                 sd2[wid] = a;
  }
}

// ================= k_agg2: layer-2 aggregation, 32 edges in flight =================

__global__ __launch_bounds__(256) void k_agg2(
    const int* __restrict__ rs, const int* __restrict__ csr,
    const float* __restrict__ ss2, const float* __restrict__ sd2,
    const _Float16* __restrict__ h2, float* __restrict__ out) {
  int wid = (blockIdx.x * 256 + threadIdx.x) >> 6;
  if (wid >= N_NODES) return;
  int lane = threadIdx.x & 63;
  int g = lane >> 2, q = lane & 3;
  int start = rs[wid], deg = rs[wid + 1] - start;
  float sd = sd2[wid];
  float a0 = 0.f, a1 = 0.f, a2 = 0.f, a3 = 0.f, dsum = 0.f;
  for (int j0 = 0; j0 < deg; j0 += 32) {
    int jA = j0 + g, jB = j0 + 16 + g;
    int sA = csr[start + (jA < deg ? jA : 0)];
    int sB = csr[start + (jB < deg ? jB : 0)];
    float eA = ss2[sA], eB = ss2[sB];
    half4 hA = *(const half4*)(h2 + (size_t)sA * C2 + q * 4);
    half4 hB = *(const half4*)(h2 + (size_t)sB * C2 + q * 4);
    float alA = (jA < deg) ? __expf(lrelu(eA + sd)) : 0.f;
    float alB = (jB < deg) ? __expf(lrelu(eB + sd)) : 0.f;
    dsum += alA + alB;
    a0 = fmaf(alA, (float)hA[0], fmaf(alB, (float)hB[0], a0));
    a1 = fmaf(alA, (float)hA[1], fmaf(alB, (float)hB[1], a1));
    a2 = fmaf(alA, (float)hA[2], fmaf(alB, (float)hB[2], a2));
    a3 = fmaf(alA, (float)hA[3], fmaf(alB, (float)hB[3], a3));
  }
#pragma unroll
  for (int off = 4; off <= 32; off <<= 1) {
    a0 += __shfl_xor(a0, off); a1 += __shfl_xor(a1, off);
    a2 += __shfl_xor(a2, off); a3 += __shfl_xor(a3, off);
    dsum += __shfl_xor(dsum, off);
  }
  if (g == 0) {
    float inv = 1.f / (dsum + EPS_);
    float4 o = make_float4(a0 * inv, a1 * inv, a2 * inv, a3 * inv);
    *(float4*)(out + (size_t)wid * C2 + q * 4) = o;
  }
}

// ================= launch: 7 dispatches =================

extern "C" void kernel_launch(void* const* d_in, const int* in_sizes, int n_in,
                              void* d_out, int out_size, void* d_ws, size_t ws_size,
                              hipStream_t stream) {
  const float* x    = (const float*)d_in[0];
  const int* senders   = (const int*)d_in[1];
  const int* receivers = (const int*)d_in[2];
  const float* W1  = (const float*)d_in[3];
  const float* a1s = (const float*)d_in[4];
  const float* a1d = (const float*)d_in[5];
  const float* W2  = (const float*)d_in[6];
  const float* a2s = (const float*)d_in[7];
  const float* a2d = (const float*)d_in[8];
  float* out = (float*)d_out;

  char* w = (char*)d_ws;
  _Float16* h1   = (_Float16*)(w + 0);          // 12,800,000 B [N][64]
  _Float16* ssh1 = (_Float16*)(w + 12800000);   //    800,000 B [N][4]
  float* sd1 = (float*)(w + 13600000);          //  1,600,000 B [N][4]
  _Float16* h2   = (_Float16*)(w + 15200000);   //  3,200,000 B [N][16]
  float* ss2 = (float*)(w + 18400000);          //    400,000 B [N]
  float* sd2 = (float*)(w + 18800000);          //    400,000 B [N]
  int*   rs  = (int*)  (w + 19200000);          //    400,128 B [N+1]
  int*   csr = (int*)  (w + 19600128);          //  6,400,000 B
  unsigned* tmp = (unsigned*)(w + 26000128);    //  6,400,000 B
  int*   M   = (int*)  (w + 32400128);          //    262,144 B [256][256]
  int*   bs2 = (int*)  (w + 32662272);          //        256 B
  // total ~32.7 MB

  k_h1g <<<G1B + NHB, 1024, 0, stream>>>(x, W1, a1s, a1d, h1, ssh1, sd1, receivers, M);
  k_scanA<<<64, 1024, 0, stream>>>(M, bs2);
  k_scanB<<<64, 1024, 0, stream>>>(M, bs2);
  k_p1  <<<NHB, 1024, 0, stream>>>(receivers, senders, M, tmp);
  k_p2  <<<NBUCK, 1024, 0, stream>>>(M, tmp, rs, csr);
  k_agg1<<<25000, 256, 0, stream>>>(rs, csr, ssh1, sd1, h1, W2, a2s, a2d, h2, ss2, sd2);
  k_agg2<<<25000, 256, 0, stream>>>(rs, csr, ss2, sd2, h2, out);
}

// Round 11
// 235.985 us; speedup vs baseline: 1.6415x; 1.3476x over previous
//
#include <hip/hip_runtime.h>

#define N_NODES 100000
#define N_EDGES 1600000
#define IN_DIM  128
#define C1      64     // hidden = 4 heads * 16
#define H1      4
#define F1      16
#define C2      16
#define NEG     0.2f
#define EPS_    1e-9f

#define NHB     256            // hist blocks (and matrix columns)
#define EPB     (N_EDGES/NHB)  // 6250 edges per hist/p1 block
#define G1B     391            // gemm1 blocks in fused kernel
#define NBUCK   196            // ceil(100000/512) non-empty buckets

typedef _Float16 half8 __attribute__((ext_vector_type(8)));
typedef _Float16 half4 __attribute__((ext_vector_type(4)));
typedef float float4v __attribute__((ext_vector_type(4)));

__device__ __forceinline__ float lrelu(float x) { return x > 0.f ? x : NEG * x; }

// ================= k_h1g: layer-1 GEMM (MFMA, LDS-built WT1) + bucket hist =================
// Blocks 0..G1B-1: gemm (16 waves x 16 nodes), WT1 built in LDS.
// Blocks G1B..G1B+255: LDS histogram of recv>>9 into M[bin][hb]. No global atomics.

__global__ __launch_bounds__(1024) void k_h1g(
    const float* __restrict__ x, const float* __restrict__ W1,
    const float* __restrict__ a1s, const float* __restrict__ a1d,
    _Float16* __restrict__ h1, _Float16* __restrict__ ssh, float* __restrict__ sd,
    const int* __restrict__ recv, int* __restrict__ M) {
  __shared__ _Float16 WT1L[80 * 136];   // rows 0-63 W1cat^T, 64-71 fused a-vecs; +8 pad
  __shared__ int hc[NHB];
  int b = blockIdx.x, t = threadIdx.x;

  if (b >= G1B) {                       // ---- histogram part ----
    int hb = b - G1B;
    if (t < NHB) hc[t] = 0;
    __syncthreads();
    int e1 = (hb + 1) * EPB;
    for (int e = hb * EPB + t; e < e1; e += 1024)
      atomicAdd(&hc[recv[e] >> 9], 1);  // LDS atomic
    __syncthreads();
    if (t < NHB) M[t * NHB + hb] = hc[t];
    return;
  }

  // ---- build WT1 in LDS ----
  for (int i = t; i < 80 * 128; i += 1024) {
    int c = i >> 7, k = i & 127;
    float v;
    if (c < 64) v = W1[(c >> 4) * 2048 + k * 16 + (c & 15)];
    else {
      int h = (c - 64) & 3;
      const float* a = (c < 68) ? a1s : a1d;
      float s = 0.f;
      for (int f = 0; f < 16; ++f) s += W1[h * 2048 + k * 16 + f] * a[h * 16 + f];
      v = s;
    }
    WT1L[c * 136 + k] = (_Float16)v;
  }
  __syncthreads();

  int wave = b * 16 + (t >> 6);
  int n0 = wave * 16;
  if (n0 >= N_NODES) return;
  int lane = t & 63;
  int mrow = lane & 15, quad = lane >> 4;
  const float* xrow = x + (size_t)(n0 + mrow) * IN_DIM + quad * 8;
  float4v acc[5];
#pragma unroll
  for (int i = 0; i < 5; ++i) acc[i] = (float4v)(0.f);
#pragma unroll
  for (int kt = 0; kt < 4; ++kt) {
    float4 a0 = *(const float4*)(xrow + kt * 32);
    float4 a1 = *(const float4*)(xrow + kt * 32 + 4);
    half8 af;
    af[0] = (_Float16)a0.x; af[1] = (_Float16)a0.y; af[2] = (_Float16)a0.z; af[3] = (_Float16)a0.w;
    af[4] = (_Float16)a1.x; af[5] = (_Float16)a1.y; af[6] = (_Float16)a1.z; af[7] = (_Float16)a1.w;
#pragma unroll
    for (int i = 0; i < 5; ++i) {
      half8 bf = *(const half8*)(WT1L + (i * 16 + mrow) * 136 + kt * 32 + quad * 8);
      acc[i] = __builtin_amdgcn_mfma_f32_16x16x32_f16(af, bf, acc[i], 0, 0, 0);
    }
  }
#pragma unroll
  for (int i = 0; i < 4; ++i)
#pragma unroll
    for (int r = 0; r < 4; ++r)
      h1[(size_t)(n0 + quad * 4 + r) * C1 + i * 16 + mrow] = (_Float16)acc[i][r];
  if (mrow < 8) {
#pragma unroll
    for (int r = 0; r < 4; ++r) {
      int n = n0 + quad * 4 + r;
      float v = acc[4][r];
      if (mrow < 4) ssh[n * 4 + mrow] = (_Float16)v;
      else          sd[n * 4 + (mrow - 4)] = v;
    }
  }
}

// ================= k_p1s: fused coalesced matrix-scan + edge placement =================
// Each block derives its 256 cursors from M directly:
//   cur[bin] = rowscan[bin] + sum_{hb<blk} M[bin][hb]
// Rows read COALESCED (64 lanes x 4 contiguous entries) — unlike the R9 stride-98
// version. Block 0 also emits bucket starts for p2. Kills both scan dispatches.

__global__ __launch_bounds__(1024) void k_p1s(
    const int* __restrict__ recv, const int* __restrict__ send,
    const int* __restrict__ M, unsigned* __restrict__ tmp, int* __restrict__ bstart) {
  __shared__ int rsum[NHB], rpart[NHB], rscan[NHB], cur[NHB];
  int blk = blockIdx.x, t = threadIdx.x;
  int wv = t >> 6, l = t & 63;
  for (int pass = 0; pass < 16; ++pass) {     // 16 waves x 16 passes = 256 rows
    int row = pass * 16 + wv;
    int s = 0, p = 0;
#pragma unroll
    for (int c4 = 0; c4 < 4; ++c4) {
      int col = c4 * 64 + l;
      int v = M[row * NHB + col];
      s += v;
      p += (col < blk) ? v : 0;
    }
#pragma unroll
    for (int off = 1; off < 64; off <<= 1) {
      s += __shfl_xor(s, off);
      p += __shfl_xor(p, off);
    }
    if (l == 0) { rsum[row] = s; rpart[row] = p; }
  }
  __syncthreads();
  if (t < 64) {                               // exclusive scan of 256 rowsums
    int a0 = rsum[4 * t], a1 = rsum[4 * t + 1], a2 = rsum[4 * t + 2], a3 = rsum[4 * t + 3];
    int tot = a0 + a1 + a2 + a3, sc = tot;
#pragma unroll
    for (int off = 1; off < 64; off <<= 1) { int u = __shfl_up(sc, off); if (t >= off) sc += u; }
    int ex = sc - tot;
    rscan[4 * t] = ex; rscan[4 * t + 1] = ex + a0;
    rscan[4 * t + 2] = ex + a0 + a1; rscan[4 * t + 3] = ex + a0 + a1 + a2;
  }
  __syncthreads();
  if (t < NHB) cur[t] = rscan[t] + rpart[t];
  if (blk == 0 && t < NHB) bstart[t] = rscan[t];
  if (blk == 0 && t == 0) bstart[NHB] = N_EDGES;
  __syncthreads();
  int e1 = (blk + 1) * EPB;
  for (int e = blk * EPB + t; e < e1; e += 1024) {
    int r = recv[e], s = send[e];
    int pos = atomicAdd(&cur[r >> 9], 1);     // LDS returning atomic
    tmp[pos] = ((unsigned)(r & 511) << 17) | (unsigned)s;
  }
}

// ================= p2: per-bucket counting sort -> rs + csr =================

__global__ __launch_bounds__(1024) void k_p2(
    const int* __restrict__ bstart, const unsigned* __restrict__ tmp,
    int* __restrict__ rs, int* __restrict__ csr) {
  __shared__ int cnt[512];
  __shared__ int wt[8];
  int b = blockIdx.x, t = threadIdx.x;
  int e0 = bstart[b];
  int e1 = bstart[b + 1];
  if (t < 512) cnt[t] = 0;
  __syncthreads();
  for (int e = e0 + t; e < e1; e += 1024)
    atomicAdd(&cnt[tmp[e] >> 17], 1);
  __syncthreads();
  int v = (t < 512) ? cnt[t] : 0;
  int l = t & 63, s = v;
#pragma unroll
  for (int off = 1; off < 64; off <<= 1) { int u = __shfl_up(s, off); if (l >= off) s += u; }
  if (t < 512 && l == 63) wt[t >> 6] = s;
  __syncthreads();
  if (t < 8) {
    int p = wt[t];
#pragma unroll
    for (int off = 1; off < 8; off <<= 1) { int u = __shfl_up(p, off); if (t >= off) p += u; }
    wt[t] = p;
  }
  __syncthreads();
  int base = (t >= 64 && t < 512) ? wt[(t >> 6) - 1] : 0;
  int excl = e0 + base + s - v;
  int idx = b * 512 + t;
  if (t < 512 && idx <= N_NODES) rs[idx] = excl;
  __syncthreads();
  if (t < 512) cnt[t] = excl;
  __syncthreads();
  for (int e = e0 + t; e < e1; e += 1024) {
    unsigned u = tmp[e];
    int pos = atomicAdd(&cnt[u >> 17], 1);
    csr[pos] = (int)(u & 0x1FFFFu);
  }
}

// ================= k_agg1: layer-1 aggregation, 16 edges in flight (R7-proven) =================

__global__ __launch_bounds__(256) void k_agg1(
    const int* __restrict__ rs, const int* __restrict__ csr,
    const _Float16* __restrict__ ssh, const float* __restrict__ sdst,
    const _Float16* __restrict__ h1, _Float16* __restrict__ z) {
  int wid = (blockIdx.x * 256 + threadIdx.x) >> 6;
  if (wid >= N_NODES) return;
  int lane = threadIdx.x & 63;
  int g = lane >> 4, f = lane & 15, h = f >> 2;
  int start = rs[wid], deg = rs[wid + 1] - start;
  float sdh = sdst[wid * 4 + h];
  float a0 = 0.f, a1 = 0.f, a2 = 0.f, a3 = 0.f, dsum = 0.f;
  for (int j0 = 0; j0 < deg; j0 += 16) {
    int jA = j0 + g, jB = j0 + 4 + g, jC = j0 + 8 + g, jD = j0 + 12 + g;
    int sA = csr[start + (jA < deg ? jA : 0)];
    int sB = csr[start + (jB < deg ? jB : 0)];
    int sC = csr[start + (jC < deg ? jC : 0)];
    int sD = csr[start + (jD < deg ? jD : 0)];
    float eA = (float)ssh[sA * 4 + h];
    float eB = (float)ssh[sB * 4 + h];
    float eC = (float)ssh[sC * 4 + h];
    float eD = (float)ssh[sD * 4 + h];
    half4 hA = *(const half4*)(h1 + (size_t)sA * C1 + f * 4);
    half4 hB = *(const half4*)(h1 + (size_t)sB * C1 + f * 4);
    half4 hC = *(const half4*)(h1 + (size_t)sC * C1 + f * 4);
    half4 hD = *(const half4*)(h1 + (size_t)sD * C1 + f * 4);
    float alA = (jA < deg) ? __expf(lrelu(eA + sdh)) : 0.f;
    float alB = (jB < deg) ? __expf(lrelu(eB + sdh)) : 0.f;
    float alC = (jC < deg) ? __expf(lrelu(eC + sdh)) : 0.f;
    float alD = (jD < deg) ? __expf(lrelu(eD + sdh)) : 0.f;
    dsum += (alA + alB) + (alC + alD);
    a0 = fmaf(alA, (float)hA[0], fmaf(alB, (float)hB[0], fmaf(alC, (float)hC[0], fmaf(alD, (float)hD[0], a0))));
    a1 = fmaf(alA, (float)hA[1], fmaf(alB, (float)hB[1], fmaf(alC, (float)hC[1], fmaf(alD, (float)hD[1], a1))));
    a2 = fmaf(alA, (float)hA[2], fmaf(alB, (float)hB[2], fmaf(alC, (float)hC[2], fmaf(alD, (float)hD[2], a2))));
    a3 = fmaf(alA, (float)hA[3], fmaf(alB, (float)hB[3], fmaf(alC, (float)hC[3], fmaf(alD, (float)hD[3], a3))));
  }
#pragma unroll
  for (int off = 16; off <= 32; off <<= 1) {
    a0 += __shfl_xor(a0, off); a1 += __shfl_xor(a1, off);
    a2 += __shfl_xor(a2, off); a3 += __shfl_xor(a3, off);
    dsum += __shfl_xor(dsum, off);
  }
  if (g == 0) {
    float inv = 1.f / (dsum + EPS_);
    float v0 = a0 * inv, v1 = a1 * inv, v2 = a2 * inv, v3 = a3 * inv;
    half4 o;
    o[0] = (_Float16)(v0 > 0.f ? v0 : __expf(v0) - 1.f);
    o[1] = (_Float16)(v1 > 0.f ? v1 : __expf(v1) - 1.f);
    o[2] = (_Float16)(v2 > 0.f ? v2 : __expf(v2) - 1.f);
    o[3] = (_Float16)(v3 > 0.f ? v3 : __expf(v3) - 1.f);
    *(half4*)(z + (size_t)wid * C1 + f * 4) = o;
  }
}

// ================= k_gemm2: MFMA, WT2 built in LDS (rows 18-31 zero) =================

__global__ __launch_bounds__(256) void k_gemm2(
    const _Float16* __restrict__ z, const float* __restrict__ W2,
    const float* __restrict__ a2s, const float* __restrict__ a2d,
    _Float16* __restrict__ h2, float* __restrict__ ss2, float* __restrict__ sd2) {
  __shared__ _Float16 WT2L[32 * 64];
  int t = threadIdx.x;
  for (int i = t; i < 32 * 64; i += 256) {
    int c = i >> 6, k = i & 63;
    float v = 0.f;
    if (c < 16) v = W2[k * 16 + c];
    else if (c == 16) { for (int f = 0; f < 16; ++f) v += W2[k * 16 + f] * a2s[f]; }
    else if (c == 17) { for (int f = 0; f < 16; ++f) v += W2[k * 16 + f] * a2d[f]; }
    WT2L[i] = (_Float16)v;
  }
  __syncthreads();
  int wave = blockIdx.x * 4 + (t >> 6);
  int n0 = wave * 16;
  if (n0 >= N_NODES) return;
  int lane = t & 63;
  int mrow = lane & 15, quad = lane >> 4;
  float4v acc0 = (float4v)(0.f), acc1 = (float4v)(0.f);
#pragma unroll
  for (int kt = 0; kt < 2; ++kt) {
    half8 af = *(const half8*)(z + (size_t)(n0 + mrow) * C1 + kt * 32 + quad * 8);
    half8 b0 = *(const half8*)(WT2L + (0 * 16 + mrow) * C1 + kt * 32 + quad * 8);
    half8 b1 = *(const half8*)(WT2L + (1 * 16 + mrow) * C1 + kt * 32 + quad * 8);
    acc0 = __builtin_amdgcn_mfma_f32_16x16x32_f16(af, b0, acc0, 0, 0, 0);
    acc1 = __builtin_amdgcn_mfma_f32_16x16x32_f16(af, b1, acc1, 0, 0, 0);
  }
#pragma unroll
  for (int r = 0; r < 4; ++r)
    h2[(size_t)(n0 + quad * 4 + r) * C2 + mrow] = (_Float16)acc0[r];
  if (mrow == 0) {
#pragma unroll
    for (int r = 0; r < 4; ++r) ss2[n0 + quad * 4 + r] = acc1[r];
  } else if (mrow == 1) {
#pragma unroll
    for (int r = 0; r < 4; ++r) sd2[n0 + quad * 4 + r] = acc1[r];
  }
}

// ================= k_agg2: layer-2 aggregation, 32 edges in flight =================

__global__ __launch_bounds__(256) void k_agg2(
    const int* __restrict__ rs, const int* __restrict__ csr,
    const float* __restrict__ ss2, const float* __restrict__ sd2,
    const _Float16* __restrict__ h2, float* __restrict__ out) {
  int wid = (blockIdx.x * 256 + threadIdx.x) >> 6;
  if (wid >= N_NODES) return;
  int lane = threadIdx.x & 63;
  int g = lane >> 2, q = lane & 3;
  int start = rs[wid], deg = rs[wid + 1] - start;
  float sd = sd2[wid];
  float a0 = 0.f, a1 = 0.f, a2 = 0.f, a3 = 0.f, dsum = 0.f;
  for (int j0 = 0; j0 < deg; j0 += 32) {
    int jA = j0 + g, jB = j0 + 16 + g;
    int sA = csr[start + (jA < deg ? jA : 0)];
    int sB = csr[start + (jB < deg ? jB : 0)];
    float eA = ss2[sA], eB = ss2[sB];
    half4 hA = *(const half4*)(h2 + (size_t)sA * C2 + q * 4);
    half4 hB = *(const half4*)(h2 + (size_t)sB * C2 + q * 4);
    float alA = (jA < deg) ? __expf(lrelu(eA + sd)) : 0.f;
    float alB = (jB < deg) ? __expf(lrelu(eB + sd)) : 0.f;
    dsum += alA + alB;
    a0 = fmaf(alA, (float)hA[0], fmaf(alB, (float)hB[0], a0));
    a1 = fmaf(alA, (float)hA[1], fmaf(alB, (float)hB[1], a1));
    a2 = fmaf(alA, (float)hA[2], fmaf(alB, (float)hB[2], a2));
    a3 = fmaf(alA, (float)hA[3], fmaf(alB, (float)hB[3], a3));
  }
#pragma unroll
  for (int off = 4; off <= 32; off <<= 1) {
    a0 += __shfl_xor(a0, off); a1 += __shfl_xor(a1, off);
    a2 += __shfl_xor(a2, off); a3 += __shfl_xor(a3, off);
    dsum += __shfl_xor(dsum, off);
  }
  if (g == 0) {
    float inv = 1.f / (dsum + EPS_);
    float4 o = make_float4(a0 * inv, a1 * inv, a2 * inv, a3 * inv);
    *(float4*)(out + (size_t)wid * C2 + q * 4) = o;
  }
}

// ================= launch: 6 dispatches =================

extern "C" void kernel_launch(void* const* d_in, const int* in_sizes, int n_in,
                              void* d_out, int out_size, void* d_ws, size_t ws_size,
                              hipStream_t stream) {
  const float* x    = (const float*)d_in[0];
  const int* senders   = (const int*)d_in[1];
  const int* receivers = (const int*)d_in[2];
  const float* W1  = (const float*)d_in[3];
  const float* a1s = (const float*)d_in[4];
  const float* a1d = (const float*)d_in[5];
  const float* W2  = (const float*)d_in[6];
  const float* a2s = (const float*)d_in[7];
  const float* a2d = (const float*)d_in[8];
  float* out = (float*)d_out;

  char* w = (char*)d_ws;
  _Float16* h1   = (_Float16*)(w + 0);          // 12,800,000 B [N][64]
  _Float16* z    = (_Float16*)(w + 12800000);   // 12,800,000 B
  _Float16* ssh1 = (_Float16*)(w + 25600000);   //    800,000 B [N][4]
  float* sd1 = (float*)(w + 26400000);          //  1,600,000 B [N][4]
  _Float16* h2   = (_Float16*)(w + 28000000);   //  3,200,000 B [N][16]
  float* ss2 = (float*)(w + 31200000);          //    400,000 B [N]
  float* sd2 = (float*)(w + 31600000);          //    400,000 B [N]
  int*   rs  = (int*)  (w + 32000000);          //    400,128 B [N+1]
  int*   csr = (int*)  (w + 32400128);          //  6,400,000 B
  unsigned* tmp = (unsigned*)(w + 38800128);    //  6,400,000 B
  int*   M   = (int*)  (w + 45200128);          //    262,144 B [256][256]
  int*   bst = (int*)  (w + 45462272);          //      1,028 B [257]
  // total ~45.5 MB

  k_h1g <<<G1B + NHB, 1024, 0, stream>>>(x, W1, a1s, a1d, h1, ssh1, sd1, receivers, M);
  k_p1s <<<NHB, 1024, 0, stream>>>(receivers, senders, M, tmp, bst);
  k_p2  <<<NBUCK, 1024, 0, stream>>>(bst, tmp, rs, csr);
  k_agg1<<<25000, 256, 0, stream>>>(rs, csr, ssh1, sd1, h1, z);
  k_gemm2<<<1563, 256, 0, stream>>>(z, W2, a2s, a2d, h2, ss2, sd2);
  k_agg2<<<25000, 256, 0, stream>>>(rs, csr, ss2, sd2, h2, out);
}